// Round 6
// baseline (446.957 us; speedup 1.0000x reference)
//
#include <hip/hip_runtime.h>

// KnowledgeGNN forward, fp32 I/O. Sizes fixed per reference.
#define Dd   64
#define Tt   4096
#define Nn   20000
#define Mm   24096      // T + N
#define Ee   100000
#define Rr   50
#define TOK  768

// k_prep block-range layout: tok | nodes | relid | W | zero
#define NB_TOK   512      // Tt/8 rows per block
#define NB_NODES 1250     // Nn*16/256
#define NB_RELID 4883     // ceil(Ee*Rr/1024)
#define NB_W     800      // Rr*4096/256
#define NB_ZERO  95       // ceil((Mm+8)/256)
// k_mid block-range layout: hist | U | p1
#define NBM_HIST 391
#define NBM_U    13
#define NBM_P    6024     // Mm/4 rows, 1 row per wave
// k_attf: fill | att
#define NBA_FILL 391
#define NBA_ATT  2048
// k_out: gemm tiles (128x128, fx direct-from-global, w in LDS) FIRST, then loss blocks
#define NKGE     391      // ceil(ceil(E/64)/4) : 1564 wave-chunks of 64 edges
#define NNT      95       // ceil(Mm/256)
#define NFIN     (NKGE+NNT)
#define NGROW    189      // ceil(Mm/128) row tiles
#define NGCOL    6        // 768/128 col chunks
#define NGEMMT   (NGROW*NGCOL)   // 1134

__device__ __forceinline__ float waveRed(float v){
  #pragma unroll
  for(int o=32;o;o>>=1) v += __shfl_xor(v,o,64);
  return v;
}

// ---------------- K1: fused prep ----------------
__global__ __launch_bounds__(256) void k_prep(
    const float* __restrict__ A, const float* __restrict__ wl1, const float* __restrict__ bl1,
    const int* __restrict__ ids, const float* __restrict__ kg,
    const float* __restrict__ ea, int* __restrict__ relid,
    const float* __restrict__ rel, const float* __restrict__ w2, const float* __restrict__ b2,
    float* __restrict__ W, int* __restrict__ deg, float* __restrict__ S,
    float* __restrict__ x){
  __shared__ float As[8*TOK];                // 24 KB, used by tok section only
  int b = blockIdx.x;
  const int t = threadIdx.x, lane = t&63, wave = t>>6;
  if(b < NB_TOK){
    // x[0:T] = A @ wl1 + bl1 ; 8 rows/block staged in LDS (coalesced), 2 rows/wave
    const int rbase = b*8;
    #pragma unroll
    for(int i=0;i<6;i++){
      int f = t + 256*i;                     // 1536 float4s = 8 rows x 192
      int row = f/192, c4 = (f - row*192)*4;
      *(float4*)&As[row*TOK + c4] = *(const float4*)&A[(size_t)(rbase+row)*TOK + c4];
    }
    __syncthreads();
    const int r0 = wave*2, r1 = r0+1;
    float a0=bl1[lane], a1=a0, c0=0.f, c1=0.f;
    for(int k=0;k<TOK;k+=2){
      float w0 = wl1[(size_t)k*Dd + lane];
      float w1 = wl1[(size_t)(k+1)*Dd + lane];
      a0 += As[r0*TOK+k]*w0;  c0 += As[r0*TOK+k+1]*w1;
      a1 += As[r1*TOK+k]*w0;  c1 += As[r1*TOK+k+1]*w1;
    }
    x[(size_t)(rbase+r0)*Dd + lane] = a0+c0;
    x[(size_t)(rbase+r1)*Dd + lane] = a1+c1;
  } else if(b < NB_TOK+NB_NODES){
    int tt = (b-NB_TOK)*256 + t;             // Nn*16 threads, float4 gather
    int i = tt>>4, c = tt&15;
    ((float4*)x)[(size_t)(Tt+i)*16 + c] = ((const float4*)kg)[(size_t)ids[i]*16 + c];
  } else if(b < NB_TOK+NB_NODES+NB_RELID){
    int tt = (b-NB_TOK-NB_NODES)*256 + t;
    size_t g4 = (size_t)tt*4;
    if(g4 < (size_t)Ee*Rr){
      float4 v = *(const float4*)&ea[g4];
      #pragma unroll
      for(int j=0;j<4;j++){
        if(((const float*)&v)[j] > 0.5f){
          unsigned g = (unsigned)(g4 + j);
          unsigned e = g / 50u;
          relid[e] = (int)(g - e*50u);
        }
      }
    }
  } else if(b < NB_TOK+NB_NODES+NB_RELID+NB_W){
    int tt = (b-NB_TOK-NB_NODES-NB_RELID)*256 + t;   // R*4096
    int r = tt>>12, j = tt&4095;
    float acc = b2[j];
    const float* rp = rel + r*Dd;
    #pragma unroll 8
    for(int d=0;d<Dd;d++) acc += rp[d] * w2[(size_t)d*4096 + j];
    W[tt] = acc > 0.f ? acc : 0.f;
  } else {
    int tt = (b-NB_TOK-NB_NODES-NB_RELID-NB_W)*256 + t;
    if(tt < Mm) deg[tt] = 0;
    else if(tt < Mm+8) S[tt-Mm] = 0.f;       // S[0..3] scalars, S[4] finisher counter
  }
}

// ---------------- K2: fused hist | U | p1 ----------------
__global__ __launch_bounds__(256) void k_mid(const int* __restrict__ ei,
    int* __restrict__ deg, const float* __restrict__ W,
    const float* __restrict__ a1w, const float* __restrict__ a2w,
    float* __restrict__ U1, float* __restrict__ U2,
    const float* __restrict__ x, float* __restrict__ p){
  int b = blockIdx.x;
  const int t = threadIdx.x, lane = t&63, wave = t>>6;
  if(b < NBM_HIST){
    int e = b*256 + t;
    if(e < Ee) atomicAdd(&deg[ei[Ee+e]], 1);
  } else if(b < NBM_HIST+NBM_U){
    int tt = (b-NBM_HIST)*256 + t;           // R*64 = 3200
    if(tt < Rr*Dd){
      const float* wp = W + (size_t)(tt>>6)*4096 + (size_t)(tt&63)*Dd;
      float s1 = 0.f, s2 = 0.f;
      #pragma unroll 8
      for(int o=0;o<Dd;o++){ float w = wp[o]; s1 += w*a1w[Dd+o]; s2 += w*a2w[Dd+o]; }
      U1[tt] = s1; U2[tt] = s2;
    }
  } else {
    int i = (b-NBM_HIST-NBM_U)*4 + wave;     // one row per wave, layer-1 p (no relu)
    float pv = waveRed(x[(size_t)i*Dd + lane] * a1w[lane]);
    if(lane==0) p[i] = pv;
  }
}

// ---------------- CSR scan ----------------
__global__ __launch_bounds__(1024) void k_scan(const int* __restrict__ deg,
    int* __restrict__ rowptr, int* __restrict__ cursor){
  __shared__ int ts[1024];
  int t = threadIdx.x;
  int base = t*24;
  int loc[24];
  int s = 0;
  #pragma unroll
  for(int j=0;j<24;j++){
    int idx = base+j;
    int d = (idx < Mm) ? deg[idx] : 0;
    loc[j] = s; s += d;
  }
  ts[t] = s;
  __syncthreads();
  for(int off=1; off<1024; off<<=1){
    int add = (t>=off) ? ts[t-off] : 0;
    __syncthreads();
    ts[t] += add;
    __syncthreads();
  }
  int excl = ts[t] - s;
  #pragma unroll
  for(int j=0;j<24;j++){
    int idx = base+j;
    if(idx < Mm){ int v = excl + loc[j]; rowptr[idx] = v; cursor[idx] = v; }
  }
  if(t==1023) rowptr[Mm] = ts[1023];
}

// ---------------- fused fill? | attention ----------------
// fill: eidx bucket-fill via cursor atomics (layer 1 only)
// att:  expa[e] = exp(relu?(x[src]).u_r + p[dst] + ab); S += sum
__global__ __launch_bounds__(256) void k_attf(const float* __restrict__ x,
    const int* __restrict__ ei, const int* __restrict__ relid,
    const float* __restrict__ U, const float* __restrict__ p,
    const float* __restrict__ ab, float* __restrict__ expa, float* __restrict__ S,
    int* __restrict__ cursor, int* __restrict__ eidx,
    int dorelu, int dofill){
  __shared__ float sw[4];
  int b = blockIdx.x;
  if(dofill){
    if(b < NBA_FILL){
      int e = b*256 + threadIdx.x;
      if(e < Ee){
        int d = ei[Ee+e];
        int pos = atomicAdd(&cursor[d], 1);
        eidx[pos] = e;
      }
      return;
    }
    b -= NBA_FILL;
  }
  int lane = threadIdx.x&63, wid = threadIdx.x>>6;
  int gw = b*4 + wid;                     // 8192 waves, grid-stride
  float ab0 = ab[0];
  float acc = 0.f;
  for(int e = gw; e < Ee; e += 4*NBA_ATT){
    int src = ei[e], dst = ei[Ee+e], r = relid[e];
    float xv = x[(size_t)src*Dd + lane];
    if(dorelu) xv = fmaxf(xv, 0.f);
    float v = waveRed(xv * U[r*Dd + lane]);
    float ex = expf(v + p[dst] + ab0);    // lane-uniform
    if(lane==0) expa[e] = ex;
    acc += ex;
  }
  if(lane==0) sw[wid] = acc;
  __syncthreads();
  if(threadIdx.x==0) atomicAdd(S, sw[0]+sw[1]+sw[2]+sw[3]);
}

// ---------------- aggregate + fused root matmul (+ next-layer p) ----------------
// Lane-parallel edge-index fetch: lanes 0..deg-1 pull eidx/expa/ei in ONE latency
// level each; x[src] row loads issued in unrolled batches of 8 (all in flight).
// OOB lanes carry a=0 so their (valid, x[row 0]) loads contribute exactly 0.
__global__ __launch_bounds__(256) void k_aggr(const float* __restrict__ x,
    const int* __restrict__ ei, const int* __restrict__ rowptr,
    const int* __restrict__ eidx, const float* __restrict__ expa,
    const float* __restrict__ S, const float* __restrict__ root,
    const float* __restrict__ bias, const float* __restrict__ awn,
    float* __restrict__ y, float* __restrict__ pnext, int dorelu){
  int lane = threadIdx.x&63, wid = threadIdx.x>>6;
  int dst = blockIdx.x*4 + wid;           // grid covers exactly Mm
  float invS = 1.f / S[0];
  int j0 = rowptr[dst], j1 = rowptr[dst+1];
  int deg = j1 - j0;
  float acc = 0.f;
  for(int base=0; base<deg; base+=64){
    int rem = deg - base;
    int n = rem < 64 ? rem : 64;
    float a = 0.f; int src = 0;
    if(lane < n){
      int e = eidx[j0 + base + lane];
      a = expa[e];
      src = ei[e];
    }
    for(int c=0; c<n; c+=8){               // c <= 56, so c+k <= 63: no shfl wrap
      float aj[8]; float xv[8];
      #pragma unroll
      for(int k=0;k<8;k++){
        int sj = __shfl(src, c+k, 64);
        aj[k]  = __shfl(a,   c+k, 64);
        xv[k]  = x[(size_t)sj*Dd + lane];
      }
      #pragma unroll
      for(int k=0;k<8;k++){
        float v = xv[k];
        if(dorelu) v = fmaxf(v, 0.f);
        acc += aj[k]*v;
      }
    }
  }
  acc *= invS;
  float xd = x[(size_t)dst*Dd + lane];
  if(dorelu) xd = fmaxf(xd, 0.f);
  float rsum = bias[lane];
  #pragma unroll 16
  for(int k=0;k<Dd;k++){
    float xk = __shfl(xd, k, 64);
    rsum += xk * root[k*Dd + lane];
  }
  float o = acc + rsum;
  y[(size_t)dst*Dd + lane] = o;
  if(pnext){
    float orl = fmaxf(o, 0.f);            // next layer reads relu(h)
    float pv = waveRed(orl * awn[lane]);
    if(lane==0) pnext[dst] = pv;
  }
}

// ---------------- fused: out = fx @ w_lin2 + b_lin2 | kge loss | nt loss ----------------
// GEMM: 128x128 tiles, 8x8 per thread. fx is read DIRECTLY from global (rows are
// contiguous in k; 16 lanes per col-group read identical addresses -> broadcast,
// 32 KB tile L1-resident across the k-loop). Only w staged in LDS (32 KB) -> 4
// blocks/CU, 4 waves/SIMD: stage/compute/write phases of co-resident blocks
// overlap. No transpose staging -> its 8-way bank conflicts are gone. Block order
// row-tile-major (cg = bb % 6) so a row tile's 6 col chunks run together and fx
// is HBM-fetched ~once (L3 hits after). Loss blocks fill the dispatch tail.
__global__ __launch_bounds__(256, 4) void k_out(const float* __restrict__ fx,
    const float* __restrict__ w, const float* __restrict__ b,
    const int* __restrict__ ei, const int* __restrict__ relid,
    const float* __restrict__ rel, const int* __restrict__ lab,
    const float* __restrict__ wnt, const float* __restrict__ bnt,
    float* __restrict__ S, float* __restrict__ out){
  __shared__ float ws[Dd][128];
  if(blockIdx.x < NGEMMT){
    const int bb = blockIdx.x;
    const int cg = bb % NGCOL;                   // col chunk (0..5) -- row-tile-major
    const int bx = bb / NGCOL;                   // row tile (0..188)
    const int t = threadIdx.x;
    const int r0 = bx*128, co = cg*128;
    // stage w chunk: ws[k][0..127] = w[k][co..co+127], 2048 float4s, 8/thread
    #pragma unroll
    for(int i=0;i<8;i++){
      int f = t + 256*i;
      int kk = f>>5, c4 = (f&31)*4;
      *(float4*)&ws[kk][c4] = *(const float4*)&w[(size_t)kk*TOK + co + c4];
    }
    __syncthreads();
    const int tr = t>>4, tc = t&15;
    const int rb = tr*8, cb = tc*4;              // rows rb..rb+7, cols cb..+3 & cb+64..+67
    float4 bv0 = *(const float4*)&b[co+cb];
    float4 bv1 = *(const float4*)&b[co+64+cb];
    float acc[8][8];
    #pragma unroll
    for(int i=0;i<8;i++){
      acc[i][0]=bv0.x; acc[i][1]=bv0.y; acc[i][2]=bv0.z; acc[i][3]=bv0.w;
      acc[i][4]=bv1.x; acc[i][5]=bv1.y; acc[i][6]=bv1.z; acc[i][7]=bv1.w;
    }
    // (last tile reads past Mm land in workspace (W buffer) -- valid memory,
    //  values unused because stores are row-guarded)
    const float* fp = fx + (size_t)(r0+rb)*Dd;
    #pragma unroll 2
    for(int k4=0;k4<Dd;k4+=4){
      float4 fv[8];
      #pragma unroll
      for(int i=0;i<8;i++) fv[i] = *(const float4*)&fp[(size_t)i*Dd + k4];
      #pragma unroll
      for(int kk=0;kk<4;kk++){
        float4 w0 = *(const float4*)&ws[k4+kk][cb];
        float4 w1 = *(const float4*)&ws[k4+kk][cb+64];
        float wv[8] = {w0.x,w0.y,w0.z,w0.w,w1.x,w1.y,w1.z,w1.w};
        #pragma unroll
        for(int i=0;i<8;i++){
          float av = ((const float*)&fv[i])[kk];
          #pragma unroll
          for(int j=0;j<8;j++) acc[i][j] += av*wv[j];
        }
      }
    }
    #pragma unroll
    for(int i=0;i<8;i++){
      int row = r0 + rb + i;
      if(row < Mm){
        float4 o0; o0.x=acc[i][0]; o0.y=acc[i][1]; o0.z=acc[i][2]; o0.w=acc[i][3];
        float4 o1; o1.x=acc[i][4]; o1.y=acc[i][5]; o1.z=acc[i][6]; o1.w=acc[i][7];
        *(float4*)&out[(size_t)row*TOK + co + cb] = o0;
        *(float4*)&out[(size_t)row*TOK + co + 64 + cb] = o1;
      }
    }
    return;
  }
  // ---- loss blocks ----
  {
    __shared__ float sr[4];
    const int lb2 = blockIdx.x - NGEMMT;         // 0..NFIN-1
    const int t = threadIdx.x, lane = t&63, wid = t>>6;
    float acc = 0.f;
    int slot;
    if(lb2 < NKGE){
      // kge loss: per wave, coalesce-load 64 edges' indices, then branchless
      // masked gathers (all loads independent -> deep pipelining under unroll).
      slot = 2;
      const int cb = (lb2*4 + wid)*64;           // chunk base edge
      int e = cb + lane;
      bool vld = e < Ee;
      int sv = vld ? ei[e]    : 0;
      int dv = vld ? ei[Ee+e] : 0;
      int rv = vld ? relid[e] : 47;              // r>=47 -> masked out
      #pragma unroll 8
      for(int j=0;j<64;j++){
        int r = __shfl(rv, j, 64);
        int s = __shfl(sv, j, 64);
        int d = __shfl(dv, j, 64);
        float m = (r < 47) ? 1.f : 0.f;
        float diff = fx[(size_t)s*Dd + lane] + rel[r*Dd + lane] - fx[(size_t)d*Dd + lane];
        acc += m*diff*diff;
      }
      acc = waveRed(acc);
    } else {
      // nt loss: one row per thread, streaming read of fx
      slot = 3;
      int i = (lb2 - NKGE)*256 + t;
      float contrib = 0.f;
      if(i < Mm){
        const float* r = fx + (size_t)i*Dd;
        float l0 = bnt[0], l1 = bnt[1], l2 = bnt[2];
        #pragma unroll 8
        for(int k=0;k<Dd;k++){
          float f = r[k];
          l0 += f*wnt[k*3+0]; l1 += f*wnt[k*3+1]; l2 += f*wnt[k*3+2];
        }
        float mx = fmaxf(l0, fmaxf(l1,l2));
        float lse = logf(expf(l0-mx)+expf(l1-mx)+expf(l2-mx)) + mx;
        int lb = lab[i];
        float lp = (lb==0 ? l0 : (lb==1 ? l1 : l2)) - lse;
        contrib = -lp;
      }
      acc = waveRed(contrib);
    }
    if(lane==0) sr[wid] = acc;
    __syncthreads();
    if(t==0){
      atomicAdd(&S[slot], sr[0]+sr[1]+sr[2]+sr[3]);
      __threadfence();
      int prev = atomicAdd((int*)&S[4], 1);      // finisher counter (zeroed in k_prep)
      if(prev == NFIN-1){
        float v2 = atomicAdd(&S[2], 0.f);        // device-scope coherent read
        float v3 = atomicAdd(&S[3], 0.f);
        size_t base = (size_t)Mm*TOK;
        out[base+0] = v2 / (float)(Ee*Dd);
        out[base+1] = v3 / (float)Mm;
      }
    }
  }
}

extern "C" void kernel_launch(void* const* d_in, const int* in_sizes, int n_in,
                              void* d_out, int out_size, void* d_ws, size_t ws_size,
                              hipStream_t stream) {
  const int*   node_ids = (const int*)d_in[0];
  const int*   ei       = (const int*)d_in[1];
  const float* eattr    = (const float*)d_in[2];
  const float* tokemb   = (const float*)d_in[3];
  const int*   labels   = (const int*)d_in[4];
  const float* kg       = (const float*)d_in[5];
  const float* rel      = (const float*)d_in[6];
  const float* w_e2     = (const float*)d_in[7];
  const float* b_e2     = (const float*)d_in[8];
  const float* a1w      = (const float*)d_in[9];
  const float* a1b      = (const float*)d_in[10];
  const float* root1    = (const float*)d_in[11];
  const float* bias1    = (const float*)d_in[12];
  const float* a2w      = (const float*)d_in[13];
  const float* a2b      = (const float*)d_in[14];
  const float* root2    = (const float*)d_in[15];
  const float* bias2    = (const float*)d_in[16];
  const float* wlin1    = (const float*)d_in[17];
  const float* blin1    = (const float*)d_in[18];
  const float* wlin2    = (const float*)d_in[19];
  const float* blin2    = (const float*)d_in[20];
  const float* wnt      = (const float*)d_in[21];
  const float* bnt      = (const float*)d_in[22];

  float* wsb = (float*)d_ws;
  float* x    = wsb;                      // M*64
  float* h    = x  + (size_t)Mm*Dd;
  float* fx   = h  + (size_t)Mm*Dd;
  float* W    = fx + (size_t)Mm*Dd;       // 50*4096
  float* U1   = W  + Rr*4096;             // 3200
  float* U2   = U1 + Rr*Dd;
  float* expa = U2 + Rr*Dd;               // E
  float* p    = expa + Ee;                // M
  float* S    = p + Mm;                   // 8: den1, den2, kge, nt, counter, pad
  int* relid  = (int*)(S + 8);            // E
  int* deg    = relid + Ee;               // M
  int* rowptr = deg + Mm;                 // M+1
  int* cursor = rowptr + Mm + 1;          // M
  int* eidx   = cursor + Mm;              // E
  float* out  = (float*)d_out;

  // ---- prep + CSR ----
  k_prep<<<NB_TOK+NB_NODES+NB_RELID+NB_W+NB_ZERO, 256, 0, stream>>>(
      tokemb, wlin1, blin1, node_ids, kg, eattr, relid, rel, w_e2, b_e2, W, deg, S, x);
  k_mid <<<NBM_HIST+NBM_U+NBM_P, 256, 0, stream>>>(ei, deg, W, a1w, a2w, U1, U2, x, p);
  k_scan<<<1, 1024, 0, stream>>>(deg, rowptr, cursor);

  // ---- layer 1: x -> h (attf also bucket-fills eidx; aggr writes p2 into p) ----
  k_attf<<<NBA_FILL+NBA_ATT, 256, 0, stream>>>(x, ei, relid, U1, p, a1b, expa, S,
                                               cursor, eidx, 0, 1);
  k_aggr<<<Mm/4, 256, 0, stream>>>(x, ei, rowptr, eidx, expa, S, root1, bias1, a2w, h, p, 0);

  // ---- layer 2: relu(h) -> fx ----
  k_attf<<<NBA_ATT, 256, 0, stream>>>(h, ei, relid, U2, p, a2b, expa, S+1,
                                      (int*)0, (int*)0, 1, 0);
  k_aggr<<<Mm/4, 256, 0, stream>>>(h, ei, rowptr, eidx, expa, S+1, root2, bias2,
                                   (const float*)0, fx, (float*)0, 1);

  // ---- fused output GEMM + kge-loss + nt-loss (+ scalar finisher) ----
  k_out <<<NGEMMT + NFIN, 256, 0, stream>>>(
      fx, wlin2, blin2, ei, relid, rel, labels, wnt, bnt, S, out);
}

// Round 8
// 389.625 us; speedup vs baseline: 1.1471x; 1.1471x over previous
//
#include <hip/hip_runtime.h>

// KnowledgeGNN forward, fp32 I/O. Sizes fixed per reference.
#define Dd   64
#define Tt   4096
#define Nn   20000
#define Mm   24096      // T + N
#define Ee   100000
#define Rr   50
#define TOK  768

// k_prep block-range layout: tok | nodes | relid | W | zero
#define NB_TOK   512      // Tt/8 rows per block
#define NB_NODES 1250     // Nn*16/256
#define NB_RELID 4883     // ceil(Ee*Rr/1024)
#define NB_W     800      // Rr*4096/256
#define NB_ZERO  95       // ceil((Mm+8)/256)
// k_mid block-range layout: hist | U
#define NBM_HIST 391
#define NBM_U    13
// k_scan: 1 scan block + Y1 blocks (16 rows each @1024 threads)
#define NSCAN_Y  1506     // Mm/16
// k_attf: fill | att (1 thread per edge)
#define NBA_FILL 391
#define NBA_ATT  391
// k_out: gemm tiles (128x128, round-5 structure) FIRST, then loss blocks
#define NKGE     391      // ceil(ceil(E/64)/4) : 1564 wave-chunks of 64 edges
#define NNT      95       // ceil(Mm/256)
#define NFIN     (NKGE+NNT)
#define NGROW    189      // ceil(Mm/128) row tiles
#define NGCOL    6        // 768/128 col chunks
#define NGEMMT   (NGROW*NGCOL)   // 1134

__device__ __forceinline__ float waveRed(float v){
  #pragma unroll
  for(int o=32;o;o>>=1) v += __shfl_xor(v,o,64);
  return v;
}

// ---------------- K1: fused prep ----------------
__global__ __launch_bounds__(256) void k_prep(
    const float* __restrict__ A, const float* __restrict__ wl1, const float* __restrict__ bl1,
    const int* __restrict__ ids, const float* __restrict__ kg,
    const float* __restrict__ ea, int* __restrict__ relid,
    const float* __restrict__ rel, const float* __restrict__ w2, const float* __restrict__ b2,
    float* __restrict__ W, int* __restrict__ deg, float* __restrict__ S,
    float* __restrict__ x){
  __shared__ float As[8*TOK];                // 24 KB, used by tok section only
  int b = blockIdx.x;
  const int t = threadIdx.x, lane = t&63, wave = t>>6;
  if(b < NB_TOK){
    // x[0:T] = A @ wl1 + bl1 ; 8 rows/block staged in LDS (coalesced), 2 rows/wave
    const int rbase = b*8;
    #pragma unroll
    for(int i=0;i<6;i++){
      int f = t + 256*i;                     // 1536 float4s = 8 rows x 192
      int row = f/192, c4 = (f - row*192)*4;
      *(float4*)&As[row*TOK + c4] = *(const float4*)&A[(size_t)(rbase+row)*TOK + c4];
    }
    __syncthreads();
    const int r0 = wave*2, r1 = r0+1;
    float a0=bl1[lane], a1=a0, c0=0.f, c1=0.f;
    for(int k=0;k<TOK;k+=2){
      float w0 = wl1[(size_t)k*Dd + lane];
      float w1 = wl1[(size_t)(k+1)*Dd + lane];
      a0 += As[r0*TOK+k]*w0;  c0 += As[r0*TOK+k+1]*w1;
      a1 += As[r1*TOK+k]*w0;  c1 += As[r1*TOK+k+1]*w1;
    }
    x[(size_t)(rbase+r0)*Dd + lane] = a0+c0;
    x[(size_t)(rbase+r1)*Dd + lane] = a1+c1;
  } else if(b < NB_TOK+NB_NODES){
    int tt = (b-NB_TOK)*256 + t;             // Nn*16 threads, float4 gather
    int i = tt>>4, c = tt&15;
    ((float4*)x)[(size_t)(Tt+i)*16 + c] = ((const float4*)kg)[(size_t)ids[i]*16 + c];
  } else if(b < NB_TOK+NB_NODES+NB_RELID){
    int tt = (b-NB_TOK-NB_NODES)*256 + t;
    size_t g4 = (size_t)tt*4;
    if(g4 < (size_t)Ee*Rr){
      float4 v = *(const float4*)&ea[g4];
      #pragma unroll
      for(int j=0;j<4;j++){
        if(((const float*)&v)[j] > 0.5f){
          unsigned g = (unsigned)(g4 + j);
          unsigned e = g / 50u;
          relid[e] = (int)(g - e*50u);
        }
      }
    }
  } else if(b < NB_TOK+NB_NODES+NB_RELID+NB_W){
    int tt = (b-NB_TOK-NB_NODES-NB_RELID)*256 + t;   // R*4096
    int r = tt>>12, j = tt&4095;
    float acc = b2[j];
    const float* rp = rel + r*Dd;
    #pragma unroll 8
    for(int d=0;d<Dd;d++) acc += rp[d] * w2[(size_t)d*4096 + j];
    W[tt] = acc > 0.f ? acc : 0.f;
  } else {
    int tt = (b-NB_TOK-NB_NODES-NB_RELID-NB_W)*256 + t;
    if(tt < Mm) deg[tt] = 0;
    else if(tt < Mm+8) S[tt-Mm] = 0.f;       // S[0..3] scalars, S[4] finisher counter
  }
}

// ---------------- K2: fused hist | U ----------------
__global__ __launch_bounds__(256) void k_mid(const int* __restrict__ ei,
    int* __restrict__ deg, const float* __restrict__ W,
    const float* __restrict__ a1w, const float* __restrict__ a2w,
    float* __restrict__ U1, float* __restrict__ U2){
  int b = blockIdx.x;
  const int t = threadIdx.x;
  if(b < NBM_HIST){
    int e = b*256 + t;
    if(e < Ee) atomicAdd(&deg[ei[Ee+e]], 1);
  } else {
    int tt = (b-NBM_HIST)*256 + t;           // R*64 = 3200
    if(tt < Rr*Dd){
      const float* wp = W + (size_t)(tt>>6)*4096 + (size_t)(tt&63)*Dd;
      float s1 = 0.f, s2 = 0.f;
      #pragma unroll 8
      for(int o=0;o<Dd;o++){ float w = wp[o]; s1 += w*a1w[Dd+o]; s2 += w*a2w[Dd+o]; }
      U1[tt] = s1; U2[tt] = s2;
    }
  }
}

// ---------------- CSR scan (block 0) + Y1 GEMM (blocks 1..NSCAN_Y) ----------------
// Y1[i][r] = sum_d x[i][d]*U1[r][d] (attention nbr-score); col 50 = p1[i] (x . a1w).
// One row per wave, 16 waves/block; U1T staged in LDS, x row broadcast via shfl.
__global__ __launch_bounds__(1024) void k_scan(const int* __restrict__ deg,
    int* __restrict__ rowptr, int* __restrict__ cursor,
    const float* __restrict__ x, const float* __restrict__ U1,
    const float* __restrict__ a1w, float* __restrict__ Y, float* __restrict__ p){
  __shared__ int ts[1024];
  __shared__ float UT[Dd][64];
  int t = threadIdx.x;
  if(blockIdx.x == 0){
    int base = t*24;
    int loc[24];
    int s = 0;
    #pragma unroll
    for(int j=0;j<24;j++){
      int idx = base+j;
      int d = (idx < Mm) ? deg[idx] : 0;
      loc[j] = s; s += d;
    }
    ts[t] = s;
    __syncthreads();
    for(int off=1; off<1024; off<<=1){
      int add = (t>=off) ? ts[t-off] : 0;
      __syncthreads();
      ts[t] += add;
      __syncthreads();
    }
    int excl = ts[t] - s;
    #pragma unroll
    for(int j=0;j<24;j++){
      int idx = base+j;
      if(idx < Mm){ int v = excl + loc[j]; rowptr[idx] = v; cursor[idx] = v; }
    }
    if(t==1023) rowptr[Mm] = ts[1023];
    return;
  }
  // ---- Y1 section ----
  for(int idx=t; idx<Rr*Dd; idx+=1024) UT[idx&63][idx>>6] = U1[idx];
  if(t < Dd){ UT[t][50] = a1w[t]; UT[t][51] = 0.f; }   // p1 column; 51 zeroed (idle lanes)
  __syncthreads();
  const int lane = t&63, wave = t>>6;
  const int i = (blockIdx.x-1)*16 + wave;
  float xv = x[(size_t)i*Dd + lane];
  float acc = 0.f;
  int cl = lane < 51 ? lane : 51;           // lanes 51..63 compute col 51 (zeros, unused)
  #pragma unroll 8
  for(int k=0;k<Dd;k++){
    float xk = __shfl(xv, k, 64);
    acc += xk * UT[k][cl];
  }
  if(lane < 50) Y[(size_t)i*50 + lane] = acc;
  else if(lane == 50) p[i] = acc;
}

// ---------------- Y2 GEMM: Y2[i][r] = relu(h[i]) . U2[r]; col 50 = p2 ----------------
__global__ __launch_bounds__(256) void k_y2(const float* __restrict__ h,
    const float* __restrict__ U2, const float* __restrict__ a2w,
    float* __restrict__ Y, float* __restrict__ p){
  __shared__ float UT[Dd][64];
  const int t = threadIdx.x;
  for(int idx=t; idx<Rr*Dd; idx+=256) UT[idx&63][idx>>6] = U2[idx];
  if(t < Dd){ UT[t][50] = a2w[t]; UT[t][51] = 0.f; }
  __syncthreads();
  const int lane = t&63, wave = t>>6;
  const int i = blockIdx.x*4 + wave;
  float xv = fmaxf(h[(size_t)i*Dd + lane], 0.f);
  float acc = 0.f;
  int cl = lane < 51 ? lane : 51;
  #pragma unroll 8
  for(int k=0;k<Dd;k++){
    float xk = __shfl(xv, k, 64);
    acc += xk * UT[k][cl];
  }
  if(lane < 50) Y[(size_t)i*50 + lane] = acc;
  else if(lane == 50) p[i] = acc;
}

// ---------------- fused fill? | attention (1 thread per edge) ----------------
// fill: eidx bucket-fill via cursor atomics (layer 1 only)
// att:  expa[e] = exp(Y[src][r] + p[dst] + ab); S += sum. Fully lane-parallel:
// two scalar gathers (Y 4.8MB L2/L3-resident, p 96KB L2) + exp per thread.
__global__ __launch_bounds__(256) void k_attf(const float* __restrict__ Y,
    const int* __restrict__ ei, const int* __restrict__ relid,
    const float* __restrict__ p, const float* __restrict__ ab,
    float* __restrict__ expa, float* __restrict__ S,
    int* __restrict__ cursor, int* __restrict__ eidx, int dofill){
  __shared__ float sr[4];
  int b = blockIdx.x;
  const int t = threadIdx.x, lane = t&63, wid = t>>6;
  if(dofill){
    if(b < NBA_FILL){
      int e = b*256 + t;
      if(e < Ee){
        int d = ei[Ee+e];
        int pos = atomicAdd(&cursor[d], 1);
        eidx[pos] = e;
      }
      return;
    }
    b -= NBA_FILL;
  }
  int e = b*256 + t;
  float ex = 0.f;
  if(e < Ee){
    int src = ei[e], dst = ei[Ee+e], r = relid[e];
    ex = expf(Y[(size_t)src*50 + r] + p[dst] + ab[0]);
    expa[e] = ex;
  }
  float acc = waveRed(ex);
  if(lane==0) sr[wid] = acc;
  __syncthreads();
  if(t==0) atomicAdd(S, sr[0]+sr[1]+sr[2]+sr[3]);
}

// ---------------- aggregate + fused root matmul ----------------
// Lane-parallel edge-index fetch: lanes 0..deg-1 pull eidx/expa/ei in ONE latency
// level each; x[src] row loads issued in unrolled batches of 8 (all in flight).
// OOB lanes carry a=0 so their (valid, x[row 0]) loads contribute exactly 0.
__global__ __launch_bounds__(256) void k_aggr(const float* __restrict__ x,
    const int* __restrict__ ei, const int* __restrict__ rowptr,
    const int* __restrict__ eidx, const float* __restrict__ expa,
    const float* __restrict__ S, const float* __restrict__ root,
    const float* __restrict__ bias, float* __restrict__ y, int dorelu){
  int lane = threadIdx.x&63, wid = threadIdx.x>>6;
  int dst = blockIdx.x*4 + wid;           // grid covers exactly Mm
  float invS = 1.f / S[0];
  int j0 = rowptr[dst], j1 = rowptr[dst+1];
  int deg = j1 - j0;
  float acc = 0.f;
  for(int base=0; base<deg; base+=64){
    int rem = deg - base;
    int n = rem < 64 ? rem : 64;
    float a = 0.f; int src = 0;
    if(lane < n){
      int e = eidx[j0 + base + lane];
      a = expa[e];
      src = ei[e];
    }
    for(int c=0; c<n; c+=8){               // c <= 56, so c+k <= 63: no shfl wrap
      float aj[8]; float xv[8];
      #pragma unroll
      for(int k=0;k<8;k++){
        int sj = __shfl(src, c+k, 64);
        aj[k]  = __shfl(a,   c+k, 64);
        xv[k]  = x[(size_t)sj*Dd + lane];
      }
      #pragma unroll
      for(int k=0;k<8;k++){
        float v = xv[k];
        if(dorelu) v = fmaxf(v, 0.f);
        acc += aj[k]*v;
      }
    }
  }
  acc *= invS;
  float xd = x[(size_t)dst*Dd + lane];
  if(dorelu) xd = fmaxf(xd, 0.f);
  float rsum = bias[lane];
  #pragma unroll 16
  for(int k=0;k<Dd;k++){
    float xk = __shfl(xd, k, 64);
    rsum += xk * root[k*Dd + lane];
  }
  y[(size_t)dst*Dd + lane] = acc + rsum;
}

// ---------------- fused: out = fx @ w_lin2 + b_lin2 | kge loss | nt loss ----------------
// GEMM: 128x128 tiles, 8x8 per thread -> 64 FMA per 4 ds_read_b128 per k-iter:
// FMA-bound (ds fully hidden). LDS 65KB -> 2 blocks/CU; co-resident wave's FMA
// burst hides ds latency. (round-5 structure, best measured: 58 us)
__global__ __launch_bounds__(256) void k_out(const float* __restrict__ fx,
    const float* __restrict__ w, const float* __restrict__ b,
    const int* __restrict__ ei, const int* __restrict__ relid,
    const float* __restrict__ rel, const int* __restrict__ lab,
    const float* __restrict__ wnt, const float* __restrict__ bnt,
    float* __restrict__ S, float* __restrict__ out){
  __shared__ float aT[Dd][132];
  __shared__ float ws[Dd][128];
  if(blockIdx.x < NGEMMT){
    const int bb = blockIdx.x;
    const int cg = bb / NGROW;                   // col chunk (0..5)
    const int bx = bb - cg*NGROW;                // row tile (0..188)
    const int t = threadIdx.x;
    const int r0 = bx*128, co = cg*128;
    // stage fx tile transposed: aT[k][r], 2048 float4s, 8/thread
    // (last tile reads past Mm land in workspace (W buffer) -- valid memory,
    //  values unused because stores are row-guarded)
    #pragma unroll
    for(int i=0;i<8;i++){
      int f = t + 256*i;
      int r = f>>4, k4 = (f&15)*4;
      float4 v = *(const float4*)&fx[(size_t)(r0+r)*Dd + k4];
      aT[k4+0][r]=v.x; aT[k4+1][r]=v.y; aT[k4+2][r]=v.z; aT[k4+3][r]=v.w;
    }
    // stage w chunk: ws[k][0..127] = w[k][co..co+127], 2048 float4s, 8/thread
    #pragma unroll
    for(int i=0;i<8;i++){
      int f = t + 256*i;
      int kk = f>>5, c4 = (f&31)*4;
      *(float4*)&ws[kk][c4] = *(const float4*)&w[(size_t)kk*TOK + co + c4];
    }
    __syncthreads();
    const int tr = t>>4, tc = t&15;
    const int rb = tr*8, cb = tc*4;              // rows rb..rb+7, cols cb..+3 & cb+64..+67
    float4 bv0 = *(const float4*)&b[co+cb];
    float4 bv1 = *(const float4*)&b[co+64+cb];
    float acc[8][8];
    #pragma unroll
    for(int i=0;i<8;i++){
      acc[i][0]=bv0.x; acc[i][1]=bv0.y; acc[i][2]=bv0.z; acc[i][3]=bv0.w;
      acc[i][4]=bv1.x; acc[i][5]=bv1.y; acc[i][6]=bv1.z; acc[i][7]=bv1.w;
    }
    #pragma unroll 4
    for(int k=0;k<Dd;k++){
      float4 a0 = *(const float4*)&aT[k][rb];
      float4 a1 = *(const float4*)&aT[k][rb+4];
      float4 w0 = *(const float4*)&ws[k][cb];
      float4 w1 = *(const float4*)&ws[k][cb+64];
      float av[8] = {a0.x,a0.y,a0.z,a0.w,a1.x,a1.y,a1.z,a1.w};
      float wv[8] = {w0.x,w0.y,w0.z,w0.w,w1.x,w1.y,w1.z,w1.w};
      #pragma unroll
      for(int i=0;i<8;i++){
        #pragma unroll
        for(int j=0;j<8;j++) acc[i][j] += av[i]*wv[j];
      }
    }
    #pragma unroll
    for(int i=0;i<8;i++){
      int row = r0 + rb + i;
      if(row < Mm){
        float4 o0; o0.x=acc[i][0]; o0.y=acc[i][1]; o0.z=acc[i][2]; o0.w=acc[i][3];
        float4 o1; o1.x=acc[i][4]; o1.y=acc[i][5]; o1.z=acc[i][6]; o1.w=acc[i][7];
        *(float4*)&out[(size_t)row*TOK + co + cb] = o0;
        *(float4*)&out[(size_t)row*TOK + co + 64 + cb] = o1;
      }
    }
    return;
  }
  // ---- loss blocks ----
  {
    __shared__ float sr[4];
    const int lb2 = blockIdx.x - NGEMMT;         // 0..NFIN-1
    const int t = threadIdx.x, lane = t&63, wid = t>>6;
    float acc = 0.f;
    int slot;
    if(lb2 < NKGE){
      // kge loss: per wave, coalesce-load 64 edges' indices, then branchless
      // masked gathers (all loads independent -> deep pipelining under unroll).
      slot = 2;
      const int cb = (lb2*4 + wid)*64;           // chunk base edge
      int e = cb + lane;
      bool vld = e < Ee;
      int sv = vld ? ei[e]    : 0;
      int dv = vld ? ei[Ee+e] : 0;
      int rv = vld ? relid[e] : 47;              // r>=47 -> masked out
      #pragma unroll 8
      for(int j=0;j<64;j++){
        int r = __shfl(rv, j, 64);
        int s = __shfl(sv, j, 64);
        int d = __shfl(dv, j, 64);
        float m = (r < 47) ? 1.f : 0.f;
        float diff = fx[(size_t)s*Dd + lane] + rel[r*Dd + lane] - fx[(size_t)d*Dd + lane];
        acc += m*diff*diff;
      }
      acc = waveRed(acc);
    } else {
      // nt loss: one row per thread, streaming read of fx
      slot = 3;
      int i = (lb2 - NKGE)*256 + t;
      float contrib = 0.f;
      if(i < Mm){
        const float* r = fx + (size_t)i*Dd;
        float l0 = bnt[0], l1 = bnt[1], l2 = bnt[2];
        #pragma unroll 8
        for(int k=0;k<Dd;k++){
          float f = r[k];
          l0 += f*wnt[k*3+0]; l1 += f*wnt[k*3+1]; l2 += f*wnt[k*3+2];
        }
        float mx = fmaxf(l0, fmaxf(l1,l2));
        float lse = logf(expf(l0-mx)+expf(l1-mx)+expf(l2-mx)) + mx;
        int lb = lab[i];
        float lp = (lb==0 ? l0 : (lb==1 ? l1 : l2)) - lse;
        contrib = -lp;
      }
      acc = waveRed(contrib);
    }
    if(lane==0) sr[wid] = acc;
    __syncthreads();
    if(t==0){
      atomicAdd(&S[slot], sr[0]+sr[1]+sr[2]+sr[3]);
      __threadfence();
      int prev = atomicAdd((int*)&S[4], 1);      // finisher counter (zeroed in k_prep)
      if(prev == NFIN-1){
        float v2 = atomicAdd(&S[2], 0.f);        // device-scope coherent read
        float v3 = atomicAdd(&S[3], 0.f);
        size_t base = (size_t)Mm*TOK;
        out[base+0] = v2 / (float)(Ee*Dd);
        out[base+1] = v3 / (float)Mm;
      }
    }
  }
}

extern "C" void kernel_launch(void* const* d_in, const int* in_sizes, int n_in,
                              void* d_out, int out_size, void* d_ws, size_t ws_size,
                              hipStream_t stream) {
  const int*   node_ids = (const int*)d_in[0];
  const int*   ei       = (const int*)d_in[1];
  const float* eattr    = (const float*)d_in[2];
  const float* tokemb   = (const float*)d_in[3];
  const int*   labels   = (const int*)d_in[4];
  const float* kg       = (const float*)d_in[5];
  const float* rel      = (const float*)d_in[6];
  const float* w_e2     = (const float*)d_in[7];
  const float* b_e2     = (const float*)d_in[8];
  const float* a1w      = (const float*)d_in[9];
  const float* a1b      = (const float*)d_in[10];
  const float* root1    = (const float*)d_in[11];
  const float* bias1    = (const float*)d_in[12];
  const float* a2w      = (const float*)d_in[13];
  const float* a2b      = (const float*)d_in[14];
  const float* root2    = (const float*)d_in[15];
  const float* bias2    = (const float*)d_in[16];
  const float* wlin1    = (const float*)d_in[17];
  const float* blin1    = (const float*)d_in[18];
  const float* wlin2    = (const float*)d_in[19];
  const float* blin2    = (const float*)d_in[20];
  const float* wnt      = (const float*)d_in[21];
  const float* bnt      = (const float*)d_in[22];

  float* wsb = (float*)d_ws;
  float* x    = wsb;                      // M*64
  float* h    = x  + (size_t)Mm*Dd;
  float* fx   = h  + (size_t)Mm*Dd;       // also hosts Y (M*50) before aggr2 writes it
  float* W    = fx + (size_t)Mm*Dd;       // 50*4096
  float* U1   = W  + Rr*4096;             // 3200
  float* U2   = U1 + Rr*Dd;
  float* expa = U2 + Rr*Dd;               // E
  float* p    = expa + Ee;                // M
  float* S    = p + Mm;                   // 8: den1, den2, kge, nt, counter, pad
  int* relid  = (int*)(S + 8);            // E
  int* deg    = relid + Ee;               // M
  int* rowptr = deg + Mm;                 // M+1
  int* cursor = rowptr + Mm + 1;          // M
  int* eidx   = cursor + Mm;              // E
  float* Y    = fx;                       // alias: Y1/Y2 live in fx until aggr2
  float* out  = (float*)d_out;

  // ---- prep + CSR + Y1 ----
  k_prep<<<NB_TOK+NB_NODES+NB_RELID+NB_W+NB_ZERO, 256, 0, stream>>>(
      tokemb, wlin1, blin1, node_ids, kg, eattr, relid, rel, w_e2, b_e2, W, deg, S, x);
  k_mid <<<NBM_HIST+NBM_U, 256, 0, stream>>>(ei, deg, W, a1w, a2w, U1, U2);
  k_scan<<<1+NSCAN_Y, 1024, 0, stream>>>(deg, rowptr, cursor, x, U1, a1w, Y, p);

  // ---- layer 1: x -> h (attf also bucket-fills eidx) ----
  k_attf<<<NBA_FILL+NBA_ATT, 256, 0, stream>>>(Y, ei, relid, p, a1b, expa, S,
                                               cursor, eidx, 1);
  k_aggr<<<Mm/4, 256, 0, stream>>>(x, ei, rowptr, eidx, expa, S, root1, bias1, h, 0);

  // ---- layer 2: relu(h) -> fx (Y2/p2 precomputed from h) ----
  k_y2  <<<Mm/4, 256, 0, stream>>>(h, U2, a2w, Y, p);
  k_attf<<<NBA_ATT, 256, 0, stream>>>(Y, ei, relid, p, a2b, expa, S+1,
                                      (int*)0, (int*)0, 0);
  k_aggr<<<Mm/4, 256, 0, stream>>>(h, ei, rowptr, eidx, expa, S+1, root2, bias2, fx, 1);

  // ---- fused output GEMM + kge-loss + nt-loss (+ scalar finisher) ----
  k_out <<<NGEMMT + NFIN, 256, 0, stream>>>(
      fx, wlin2, blin2, ei, relid, rel, labels, wnt, bnt, S, out);
}

// Round 9
// 365.435 us; speedup vs baseline: 1.2231x; 1.0662x over previous
//
#include <hip/hip_runtime.h>

// KnowledgeGNN forward, fp32 I/O. Sizes fixed per reference.
#define Dd   64
#define Tt   4096
#define Nn   20000
#define Mm   24096      // T + N
#define Ee   100000
#define Rr   50
#define TOK  768

// k_prep block-range layout: tok | nodes | relid | W | zero
#define NB_TOK   512      // Tt/8 rows per block
#define NB_NODES 1250     // Nn*16/256
#define NB_RELID 4883     // ceil(Ee*Rr/1024)
#define NB_W     800      // Rr*4096/256
#define NB_ZERO  95       // ceil((Mm+8)/256)
// k_mid block-range layout: hist | U
#define NBM_HIST 391
#define NBM_U    13
// k_scan: 1 scan block + Y1 blocks (16 rows each @1024 threads)
#define NSCAN_Y  1506     // Mm/16
// k_attf: fill | att (1 thread per edge)
#define NBA_FILL 391
#define NBA_ATT  391
// k_out: gemm tiles (128x128, round-5 structure) FIRST, then loss blocks
#define NKGE     391      // ceil(ceil(E/64)/4) : 1564 wave-chunks of 64 edges
#define NNT      95       // ceil(Mm/256)
#define NFIN     (NKGE+NNT)
#define NGROW    189      // ceil(Mm/128) row tiles
#define NGCOL    6        // 768/128 col chunks
#define NGEMMT   (NGROW*NGCOL)   // 1134

__device__ __forceinline__ float waveRed(float v){
  #pragma unroll
  for(int o=32;o;o>>=1) v += __shfl_xor(v,o,64);
  return v;
}

// ---------------- K1: fused prep ----------------
__global__ __launch_bounds__(256) void k_prep(
    const float* __restrict__ A, const float* __restrict__ wl1, const float* __restrict__ bl1,
    const int* __restrict__ ids, const float* __restrict__ kg,
    const float* __restrict__ ea, int* __restrict__ relid,
    const float* __restrict__ rel, const float* __restrict__ w2, const float* __restrict__ b2,
    float* __restrict__ W, int* __restrict__ deg, float* __restrict__ S,
    float* __restrict__ x){
  __shared__ float As[8*TOK];                // 24 KB, used by tok section only
  int b = blockIdx.x;
  const int t = threadIdx.x, lane = t&63, wave = t>>6;
  if(b < NB_TOK){
    // x[0:T] = A @ wl1 + bl1 ; 8 rows/block staged in LDS (coalesced), 2 rows/wave
    const int rbase = b*8;
    #pragma unroll
    for(int i=0;i<6;i++){
      int f = t + 256*i;                     // 1536 float4s = 8 rows x 192
      int row = f/192, c4 = (f - row*192)*4;
      *(float4*)&As[row*TOK + c4] = *(const float4*)&A[(size_t)(rbase+row)*TOK + c4];
    }
    __syncthreads();
    const int r0 = wave*2, r1 = r0+1;
    float a0=bl1[lane], a1=a0, c0=0.f, c1=0.f;
    for(int k=0;k<TOK;k+=2){
      float w0 = wl1[(size_t)k*Dd + lane];
      float w1 = wl1[(size_t)(k+1)*Dd + lane];
      a0 += As[r0*TOK+k]*w0;  c0 += As[r0*TOK+k+1]*w1;
      a1 += As[r1*TOK+k]*w0;  c1 += As[r1*TOK+k+1]*w1;
    }
    x[(size_t)(rbase+r0)*Dd + lane] = a0+c0;
    x[(size_t)(rbase+r1)*Dd + lane] = a1+c1;
  } else if(b < NB_TOK+NB_NODES){
    int tt = (b-NB_TOK)*256 + t;             // Nn*16 threads, float4 gather
    int i = tt>>4, c = tt&15;
    ((float4*)x)[(size_t)(Tt+i)*16 + c] = ((const float4*)kg)[(size_t)ids[i]*16 + c];
  } else if(b < NB_TOK+NB_NODES+NB_RELID){
    int tt = (b-NB_TOK-NB_NODES)*256 + t;
    size_t g4 = (size_t)tt*4;
    if(g4 < (size_t)Ee*Rr){
      float4 v = *(const float4*)&ea[g4];
      #pragma unroll
      for(int j=0;j<4;j++){
        if(((const float*)&v)[j] > 0.5f){
          unsigned g = (unsigned)(g4 + j);
          unsigned e = g / 50u;
          relid[e] = (int)(g - e*50u);
        }
      }
    }
  } else if(b < NB_TOK+NB_NODES+NB_RELID+NB_W){
    int tt = (b-NB_TOK-NB_NODES-NB_RELID)*256 + t;   // R*4096
    int r = tt>>12, j = tt&4095;
    float acc = b2[j];
    const float* rp = rel + r*Dd;
    #pragma unroll 8
    for(int d=0;d<Dd;d++) acc += rp[d] * w2[(size_t)d*4096 + j];
    W[tt] = acc > 0.f ? acc : 0.f;
  } else {
    int tt = (b-NB_TOK-NB_NODES-NB_RELID-NB_W)*256 + t;
    if(tt < Mm) deg[tt] = 0;
    else if(tt < Mm+8) S[tt-Mm] = 0.f;       // S[0..3] scalars, S[4] finisher counter
  }
}

// ---------------- K2: fused hist | U ----------------
__global__ __launch_bounds__(256) void k_mid(const int* __restrict__ ei,
    int* __restrict__ deg, const float* __restrict__ W,
    const float* __restrict__ a1w, const float* __restrict__ a2w,
    float* __restrict__ U1, float* __restrict__ U2){
  int b = blockIdx.x;
  const int t = threadIdx.x;
  if(b < NBM_HIST){
    int e = b*256 + t;
    if(e < Ee) atomicAdd(&deg[ei[Ee+e]], 1);
  } else {
    int tt = (b-NBM_HIST)*256 + t;           // R*64 = 3200
    if(tt < Rr*Dd){
      const float* wp = W + (size_t)(tt>>6)*4096 + (size_t)(tt&63)*Dd;
      float s1 = 0.f, s2 = 0.f;
      #pragma unroll 8
      for(int o=0;o<Dd;o++){ float w = wp[o]; s1 += w*a1w[Dd+o]; s2 += w*a2w[Dd+o]; }
      U1[tt] = s1; U2[tt] = s2;
    }
  }
}

// ---------------- CSR scan (block 0) + Y1 GEMM (blocks 1..NSCAN_Y) ----------------
// Y1[i][r] = sum_d x[i][d]*U1[r][d] (attention nbr-score); col 50 = p1[i] (x . a1w).
// One row per wave, 16 waves/block; U1T staged in LDS (stride 65: odd -> staging
// writes step all 32 banks, conflict-free; row reads consecutive -> free).
__global__ __launch_bounds__(1024) void k_scan(const int* __restrict__ deg,
    int* __restrict__ rowptr, int* __restrict__ cursor,
    const float* __restrict__ x, const float* __restrict__ U1,
    const float* __restrict__ a1w, float* __restrict__ Y, float* __restrict__ p){
  __shared__ int ts[1024];
  __shared__ float UT[Dd][65];
  int t = threadIdx.x;
  if(blockIdx.x == 0){
    int base = t*24;
    int loc[24];
    int s = 0;
    #pragma unroll
    for(int j=0;j<24;j++){
      int idx = base+j;
      int d = (idx < Mm) ? deg[idx] : 0;
      loc[j] = s; s += d;
    }
    ts[t] = s;
    __syncthreads();
    for(int off=1; off<1024; off<<=1){
      int add = (t>=off) ? ts[t-off] : 0;
      __syncthreads();
      ts[t] += add;
      __syncthreads();
    }
    int excl = ts[t] - s;
    #pragma unroll
    for(int j=0;j<24;j++){
      int idx = base+j;
      if(idx < Mm){ int v = excl + loc[j]; rowptr[idx] = v; cursor[idx] = v; }
    }
    if(t==1023) rowptr[Mm] = ts[1023];
    return;
  }
  // ---- Y1 section ----
  for(int idx=t; idx<Rr*Dd; idx+=1024) UT[idx&63][idx>>6] = U1[idx];
  if(t < Dd){ UT[t][50] = a1w[t]; UT[t][51] = 0.f; }   // p1 column; 51 zeroed (idle lanes)
  __syncthreads();
  const int lane = t&63, wave = t>>6;
  const int i = (blockIdx.x-1)*16 + wave;
  float xv = x[(size_t)i*Dd + lane];
  float acc = 0.f;
  int cl = lane < 51 ? lane : 51;           // lanes 51..63 compute col 51 (zeros, unused)
  #pragma unroll 8
  for(int k=0;k<Dd;k++){
    float xk = __shfl(xv, k, 64);
    acc += xk * UT[k][cl];
  }
  if(lane < 50) Y[(size_t)i*50 + lane] = acc;
  else if(lane == 50) p[i] = acc;
}

// ---------------- Y2 GEMM: Y2[i][r] = relu(h[i]) . U2[r]; col 50 = p2 ----------------
__global__ __launch_bounds__(256) void k_y2(const float* __restrict__ h,
    const float* __restrict__ U2, const float* __restrict__ a2w,
    float* __restrict__ Y, float* __restrict__ p){
  __shared__ float UT[Dd][65];               // stride 65: conflict-free staging + reads
  const int t = threadIdx.x;
  for(int idx=t; idx<Rr*Dd; idx+=256) UT[idx&63][idx>>6] = U2[idx];
  if(t < Dd){ UT[t][50] = a2w[t]; UT[t][51] = 0.f; }
  __syncthreads();
  const int lane = t&63, wave = t>>6;
  const int i = blockIdx.x*4 + wave;
  float xv = fmaxf(h[(size_t)i*Dd + lane], 0.f);
  float acc = 0.f;
  int cl = lane < 51 ? lane : 51;
  #pragma unroll 8
  for(int k=0;k<Dd;k++){
    float xk = __shfl(xv, k, 64);
    acc += xk * UT[k][cl];
  }
  if(lane < 50) Y[(size_t)i*50 + lane] = acc;
  else if(lane == 50) p[i] = acc;
}

// ---------------- fused fill? | attention (1 thread per edge) ----------------
// fill: eidx bucket-fill via cursor atomics (layer 1 only)
// att:  expa[e] = exp(Y[src][r] + p[dst] + ab); S += sum. Fully lane-parallel:
// two scalar gathers (Y 4.8MB L2/L3-resident, p 96KB L2) + exp per thread.
__global__ __launch_bounds__(256) void k_attf(const float* __restrict__ Y,
    const int* __restrict__ ei, const int* __restrict__ relid,
    const float* __restrict__ p, const float* __restrict__ ab,
    float* __restrict__ expa, float* __restrict__ S,
    int* __restrict__ cursor, int* __restrict__ eidx, int dofill){
  __shared__ float sr[4];
  int b = blockIdx.x;
  const int t = threadIdx.x, lane = t&63, wid = t>>6;
  if(dofill){
    if(b < NBA_FILL){
      int e = b*256 + t;
      if(e < Ee){
        int d = ei[Ee+e];
        int pos = atomicAdd(&cursor[d], 1);
        eidx[pos] = e;
      }
      return;
    }
    b -= NBA_FILL;
  }
  int e = b*256 + t;
  float ex = 0.f;
  if(e < Ee){
    int src = ei[e], dst = ei[Ee+e], r = relid[e];
    ex = expf(Y[(size_t)src*50 + r] + p[dst] + ab[0]);
    expa[e] = ex;
  }
  float acc = waveRed(ex);
  if(lane==0) sr[wid] = acc;
  __syncthreads();
  if(t==0) atomicAdd(S, sr[0]+sr[1]+sr[2]+sr[3]);
}

// ---------------- aggregate + fused root matmul ----------------
// Lane-parallel edge-index fetch: lanes 0..deg-1 pull eidx/expa/ei in ONE latency
// level each; x[src] row loads issued in unrolled batches of 8 (all in flight).
// OOB lanes carry a=0 so their (valid, x[row 0]) loads contribute exactly 0.
__global__ __launch_bounds__(256) void k_aggr(const float* __restrict__ x,
    const int* __restrict__ ei, const int* __restrict__ rowptr,
    const int* __restrict__ eidx, const float* __restrict__ expa,
    const float* __restrict__ S, const float* __restrict__ root,
    const float* __restrict__ bias, float* __restrict__ y, int dorelu){
  int lane = threadIdx.x&63, wid = threadIdx.x>>6;
  int dst = blockIdx.x*4 + wid;           // grid covers exactly Mm
  float invS = 1.f / S[0];
  int j0 = rowptr[dst], j1 = rowptr[dst+1];
  int deg = j1 - j0;
  float acc = 0.f;
  for(int base=0; base<deg; base+=64){
    int rem = deg - base;
    int n = rem < 64 ? rem : 64;
    float a = 0.f; int src = 0;
    if(lane < n){
      int e = eidx[j0 + base + lane];
      a = expa[e];
      src = ei[e];
    }
    for(int c=0; c<n; c+=8){               // c <= 56, so c+k <= 63: no shfl wrap
      float aj[8]; float xv[8];
      #pragma unroll
      for(int k=0;k<8;k++){
        int sj = __shfl(src, c+k, 64);
        aj[k]  = __shfl(a,   c+k, 64);
        xv[k]  = x[(size_t)sj*Dd + lane];
      }
      #pragma unroll
      for(int k=0;k<8;k++){
        float v = xv[k];
        if(dorelu) v = fmaxf(v, 0.f);
        acc += aj[k]*v;
      }
    }
  }
  acc *= invS;
  float xd = x[(size_t)dst*Dd + lane];
  if(dorelu) xd = fmaxf(xd, 0.f);
  float rsum = bias[lane];
  #pragma unroll 16
  for(int k=0;k<Dd;k++){
    float xk = __shfl(xd, k, 64);
    rsum += xk * root[k*Dd + lane];
  }
  y[(size_t)dst*Dd + lane] = acc + rsum;
}

// ---------------- fused: out = fx @ w_lin2 + b_lin2 | kge loss | nt loss ----------------
// GEMM: 128x128 tiles, 8x8 per thread -> 64 FMA per 4 ds_read_b128 per k-iter:
// FMA-bound (ds fully hidden). LDS 65KB -> 2 blocks/CU; co-resident wave's FMA
// burst hides ds latency. (round-5 structure, best measured: 58 us)
__global__ __launch_bounds__(256) void k_out(const float* __restrict__ fx,
    const float* __restrict__ w, const float* __restrict__ b,
    const int* __restrict__ ei, const int* __restrict__ relid,
    const float* __restrict__ rel, const int* __restrict__ lab,
    const float* __restrict__ wnt, const float* __restrict__ bnt,
    float* __restrict__ S, float* __restrict__ out){
  __shared__ float aT[Dd][132];
  __shared__ float ws[Dd][128];
  if(blockIdx.x < NGEMMT){
    const int bb = blockIdx.x;
    const int cg = bb / NGROW;                   // col chunk (0..5)
    const int bx = bb - cg*NGROW;                // row tile (0..188)
    const int t = threadIdx.x;
    const int r0 = bx*128, co = cg*128;
    // stage fx tile transposed: aT[k][r], 2048 float4s, 8/thread
    // (last tile reads past Mm land in workspace (W buffer) -- valid memory,
    //  values unused because stores are row-guarded)
    #pragma unroll
    for(int i=0;i<8;i++){
      int f = t + 256*i;
      int r = f>>4, k4 = (f&15)*4;
      float4 v = *(const float4*)&fx[(size_t)(r0+r)*Dd + k4];
      aT[k4+0][r]=v.x; aT[k4+1][r]=v.y; aT[k4+2][r]=v.z; aT[k4+3][r]=v.w;
    }
    // stage w chunk: ws[k][0..127] = w[k][co..co+127], 2048 float4s, 8/thread
    #pragma unroll
    for(int i=0;i<8;i++){
      int f = t + 256*i;
      int kk = f>>5, c4 = (f&31)*4;
      *(float4*)&ws[kk][c4] = *(const float4*)&w[(size_t)kk*TOK + co + c4];
    }
    __syncthreads();
    const int tr = t>>4, tc = t&15;
    const int rb = tr*8, cb = tc*4;              // rows rb..rb+7, cols cb..+3 & cb+64..+67
    float4 bv0 = *(const float4*)&b[co+cb];
    float4 bv1 = *(const float4*)&b[co+64+cb];
    float acc[8][8];
    #pragma unroll
    for(int i=0;i<8;i++){
      acc[i][0]=bv0.x; acc[i][1]=bv0.y; acc[i][2]=bv0.z; acc[i][3]=bv0.w;
      acc[i][4]=bv1.x; acc[i][5]=bv1.y; acc[i][6]=bv1.z; acc[i][7]=bv1.w;
    }
    #pragma unroll 4
    for(int k=0;k<Dd;k++){
      float4 a0 = *(const float4*)&aT[k][rb];
      float4 a1 = *(const float4*)&aT[k][rb+4];
      float4 w0 = *(const float4*)&ws[k][cb];
      float4 w1 = *(const float4*)&ws[k][cb+64];
      float av[8] = {a0.x,a0.y,a0.z,a0.w,a1.x,a1.y,a1.z,a1.w};
      float wv[8] = {w0.x,w0.y,w0.z,w0.w,w1.x,w1.y,w1.z,w1.w};
      #pragma unroll
      for(int i=0;i<8;i++){
        #pragma unroll
        for(int j=0;j<8;j++) acc[i][j] += av[i]*wv[j];
      }
    }
    #pragma unroll
    for(int i=0;i<8;i++){
      int row = r0 + rb + i;
      if(row < Mm){
        float4 o0; o0.x=acc[i][0]; o0.y=acc[i][1]; o0.z=acc[i][2]; o0.w=acc[i][3];
        float4 o1; o1.x=acc[i][4]; o1.y=acc[i][5]; o1.z=acc[i][6]; o1.w=acc[i][7];
        *(float4*)&out[(size_t)row*TOK + co + cb] = o0;
        *(float4*)&out[(size_t)row*TOK + co + 64 + cb] = o1;
      }
    }
    return;
  }
  // ---- loss blocks ----
  {
    __shared__ float sr[4];
    const int lb2 = blockIdx.x - NGEMMT;         // 0..NFIN-1
    const int t = threadIdx.x, lane = t&63, wid = t>>6;
    float acc = 0.f;
    int slot;
    if(lb2 < NKGE){
      // kge loss: per wave, coalesce-load 64 edges' indices, then branchless
      // masked gathers (all loads independent -> deep pipelining under unroll).
      slot = 2;
      const int cb = (lb2*4 + wid)*64;           // chunk base edge
      int e = cb + lane;
      bool vld = e < Ee;
      int sv = vld ? ei[e]    : 0;
      int dv = vld ? ei[Ee+e] : 0;
      int rv = vld ? relid[e] : 47;              // r>=47 -> masked out
      #pragma unroll 8
      for(int j=0;j<64;j++){
        int r = __shfl(rv, j, 64);
        int s = __shfl(sv, j, 64);
        int d = __shfl(dv, j, 64);
        float m = (r < 47) ? 1.f : 0.f;
        float diff = fx[(size_t)s*Dd + lane] + rel[r*Dd + lane] - fx[(size_t)d*Dd + lane];
        acc += m*diff*diff;
      }
      acc = waveRed(acc);
    } else {
      // nt loss: one row per thread, streaming read of fx
      slot = 3;
      int i = (lb2 - NKGE)*256 + t;
      float contrib = 0.f;
      if(i < Mm){
        const float* r = fx + (size_t)i*Dd;
        float l0 = bnt[0], l1 = bnt[1], l2 = bnt[2];
        #pragma unroll 8
        for(int k=0;k<Dd;k++){
          float f = r[k];
          l0 += f*wnt[k*3+0]; l1 += f*wnt[k*3+1]; l2 += f*wnt[k*3+2];
        }
        float mx = fmaxf(l0, fmaxf(l1,l2));
        float lse = logf(expf(l0-mx)+expf(l1-mx)+expf(l2-mx)) + mx;
        int lb = lab[i];
        float lp = (lb==0 ? l0 : (lb==1 ? l1 : l2)) - lse;
        contrib = -lp;
      }
      acc = waveRed(contrib);
    }
    if(lane==0) sr[wid] = acc;
    __syncthreads();
    if(t==0){
      atomicAdd(&S[slot], sr[0]+sr[1]+sr[2]+sr[3]);
      __threadfence();
      int prev = atomicAdd((int*)&S[4], 1);      // finisher counter (zeroed in k_prep)
      if(prev == NFIN-1){
        float v2 = atomicAdd(&S[2], 0.f);        // device-scope coherent read
        float v3 = atomicAdd(&S[3], 0.f);
        size_t base = (size_t)Mm*TOK;
        out[base+0] = v2 / (float)(Ee*Dd);
        out[base+1] = v3 / (float)Mm;
      }
    }
  }
}

extern "C" void kernel_launch(void* const* d_in, const int* in_sizes, int n_in,
                              void* d_out, int out_size, void* d_ws, size_t ws_size,
                              hipStream_t stream) {
  const int*   node_ids = (const int*)d_in[0];
  const int*   ei       = (const int*)d_in[1];
  const float* eattr    = (const float*)d_in[2];
  const float* tokemb   = (const float*)d_in[3];
  const int*   labels   = (const int*)d_in[4];
  const float* kg       = (const float*)d_in[5];
  const float* rel      = (const float*)d_in[6];
  const float* w_e2     = (const float*)d_in[7];
  const float* b_e2     = (const float*)d_in[8];
  const float* a1w      = (const float*)d_in[9];
  const float* a1b      = (const float*)d_in[10];
  const float* root1    = (const float*)d_in[11];
  const float* bias1    = (const float*)d_in[12];
  const float* a2w      = (const float*)d_in[13];
  const float* a2b      = (const float*)d_in[14];
  const float* root2    = (const float*)d_in[15];
  const float* bias2    = (const float*)d_in[16];
  const float* wlin1    = (const float*)d_in[17];
  const float* blin1    = (const float*)d_in[18];
  const float* wlin2    = (const float*)d_in[19];
  const float* blin2    = (const float*)d_in[20];
  const float* wnt      = (const float*)d_in[21];
  const float* bnt      = (const float*)d_in[22];

  float* wsb = (float*)d_ws;
  float* x    = wsb;                      // M*64
  float* h    = x  + (size_t)Mm*Dd;
  float* fx   = h  + (size_t)Mm*Dd;       // also hosts Y (M*50) before aggr2 writes it
  float* W    = fx + (size_t)Mm*Dd;       // 50*4096
  float* U1   = W  + Rr*4096;             // 3200
  float* U2   = U1 + Rr*Dd;
  float* expa = U2 + Rr*Dd;               // E
  float* p    = expa + Ee;                // M
  float* S    = p + Mm;                   // 8: den1, den2, kge, nt, counter, pad
  int* relid  = (int*)(S + 8);            // E
  int* deg    = relid + Ee;               // M
  int* rowptr = deg + Mm;                 // M+1
  int* cursor = rowptr + Mm + 1;          // M
  int* eidx   = cursor + Mm;              // E
  float* Y    = fx;                       // alias: Y1/Y2 live in fx until aggr2
  float* out  = (float*)d_out;

  // ---- prep + CSR + Y1 ----
  k_prep<<<NB_TOK+NB_NODES+NB_RELID+NB_W+NB_ZERO, 256, 0, stream>>>(
      tokemb, wlin1, blin1, node_ids, kg, eattr, relid, rel, w_e2, b_e2, W, deg, S, x);
  k_mid <<<NBM_HIST+NBM_U, 256, 0, stream>>>(ei, deg, W, a1w, a2w, U1, U2);
  k_scan<<<1+NSCAN_Y, 1024, 0, stream>>>(deg, rowptr, cursor, x, U1, a1w, Y, p);

  // ---- layer 1: x -> h (attf also bucket-fills eidx) ----
  k_attf<<<NBA_FILL+NBA_ATT, 256, 0, stream>>>(Y, ei, relid, p, a1b, expa, S,
                                               cursor, eidx, 1);
  k_aggr<<<Mm/4, 256, 0, stream>>>(x, ei, rowptr, eidx, expa, S, root1, bias1, h, 0);

  // ---- layer 2: relu(h) -> fx (Y2/p2 precomputed from h) ----
  k_y2  <<<Mm/4, 256, 0, stream>>>(h, U2, a2w, Y, p);
  k_attf<<<NBA_ATT, 256, 0, stream>>>(Y, ei, relid, p, a2b, expa, S+1,
                                      (int*)0, (int*)0, 0);
  k_aggr<<<Mm/4, 256, 0, stream>>>(h, ei, rowptr, eidx, expa, S+1, root2, bias2, fx, 1);

  // ---- fused output GEMM + kge-loss + nt-loss (+ scalar finisher) ----
  k_out <<<NGEMMT + NFIN, 256, 0, stream>>>(
      fx, wlin2, blin2, ei, relid, rel, labels, wnt, bnt, S, out);
}

// Round 11
// 358.356 us; speedup vs baseline: 1.2472x; 1.0198x over previous
//
#include <hip/hip_runtime.h>

// KnowledgeGNN forward, fp32 I/O. Sizes fixed per reference.
#define Dd   64
#define Tt   4096
#define Nn   20000
#define Mm   24096      // T + N
#define Ee   100000
#define Rr   50
#define TOK  768

// k_prep block-range layout: tok | nodes | relid | W | zero
#define NB_TOK   256      // 16 rows/block (4 rows/wave, uniform-read GEMM)
#define NB_NODES 1250     // Nn*16/256
#define NB_RELID 4883     // ceil(Ee*Rr/1024)
#define NB_W     800      // Rr*4096/256
#define NB_ZERO  95       // ceil((Mm+8)/256)
// k_mid block-range layout: hist | U
#define NBM_HIST 391
#define NBM_U    13
// k_scan: 1 scan block + Y1 blocks (64 rows each @1024 threads = 16 waves x 4 rows)
#define NSCAN_Y  377      // ceil(Mm/64)
// k_attf: fill | att (1 thread per edge)
#define NBA_FILL 391
#define NBA_ATT  391
// k_out: gemm tiles (128x128, round-5 structure) FIRST, then loss blocks
#define NKGE     391      // ceil(ceil(E/64)/4) : 1564 wave-chunks of 64 edges
#define NNT      95       // ceil(Mm/256)
#define NFIN     (NKGE+NNT)
#define NGROW    189      // ceil(Mm/128) row tiles
#define NGCOL    6        // 768/128 col chunks
#define NGEMMT   (NGROW*NGCOL)   // 1134

__device__ __forceinline__ float waveRed(float v){
  #pragma unroll
  for(int o=32;o;o>>=1) v += __shfl_xor(v,o,64);
  return v;
}

// ---------------- K1: fused prep ----------------
// tok section: x[0:T] = A @ wl1 + bl1 as 4 rows/wave. A-row values are read via
// WAVE-UNIFORM float4 loads (scalar/broadcast path -- no LDS pipe, no shfl);
// wl1 reads are coalesced and L2-resident. Replaces the LDS-staged broadcast
// loop that was LDS-pipe-bound (~30 us).
__global__ __launch_bounds__(256) void k_prep(
    const float* __restrict__ A, const float* __restrict__ wl1, const float* __restrict__ bl1,
    const int* __restrict__ ids, const float* __restrict__ kg,
    const float* __restrict__ ea, int* __restrict__ relid,
    const float* __restrict__ rel, const float* __restrict__ w2, const float* __restrict__ b2,
    float* __restrict__ W, int* __restrict__ deg, float* __restrict__ S,
    float* __restrict__ x){
  int b = blockIdx.x;
  const int t = threadIdx.x, lane = t&63;
  if(b < NB_TOK){
    const int wv = __builtin_amdgcn_readfirstlane(t>>6);
    const int r0 = b*16 + wv*4;
    const float* A0 = A + (size_t)r0*TOK;
    float bl = bl1[lane];
    float acc0=bl, acc1=bl, acc2=bl, acc3=bl;
    #pragma unroll 2
    for(int k=0;k<TOK;k+=4){
      float4 q0 = *(const float4*)&A0[k];
      float4 q1 = *(const float4*)&A0[TOK+k];
      float4 q2 = *(const float4*)&A0[2*TOK+k];
      float4 q3 = *(const float4*)&A0[3*TOK+k];
      float w0 = wl1[(size_t)k*Dd + lane];
      float w1 = wl1[(size_t)(k+1)*Dd + lane];
      float w2v= wl1[(size_t)(k+2)*Dd + lane];
      float w3 = wl1[(size_t)(k+3)*Dd + lane];
      acc0 += q0.x*w0 + q0.y*w1 + q0.z*w2v + q0.w*w3;
      acc1 += q1.x*w0 + q1.y*w1 + q1.z*w2v + q1.w*w3;
      acc2 += q2.x*w0 + q2.y*w1 + q2.z*w2v + q2.w*w3;
      acc3 += q3.x*w0 + q3.y*w1 + q3.z*w2v + q3.w*w3;
    }
    x[(size_t)(r0+0)*Dd + lane] = acc0;
    x[(size_t)(r0+1)*Dd + lane] = acc1;
    x[(size_t)(r0+2)*Dd + lane] = acc2;
    x[(size_t)(r0+3)*Dd + lane] = acc3;
  } else if(b < NB_TOK+NB_NODES){
    int tt = (b-NB_TOK)*256 + t;             // Nn*16 threads, float4 gather
    int i = tt>>4, c = tt&15;
    ((float4*)x)[(size_t)(Tt+i)*16 + c] = ((const float4*)kg)[(size_t)ids[i]*16 + c];
  } else if(b < NB_TOK+NB_NODES+NB_RELID){
    int tt = (b-NB_TOK-NB_NODES)*256 + t;
    size_t g4 = (size_t)tt*4;
    if(g4 < (size_t)Ee*Rr){
      float4 v = *(const float4*)&ea[g4];
      #pragma unroll
      for(int j=0;j<4;j++){
        if(((const float*)&v)[j] > 0.5f){
          unsigned g = (unsigned)(g4 + j);
          unsigned e = g / 50u;
          relid[e] = (int)(g - e*50u);
        }
      }
    }
  } else if(b < NB_TOK+NB_NODES+NB_RELID+NB_W){
    int tt = (b-NB_TOK-NB_NODES-NB_RELID)*256 + t;   // R*4096
    int r = tt>>12, j = tt&4095;
    float acc = b2[j];
    const float* rp = rel + r*Dd;
    #pragma unroll 8
    for(int d=0;d<Dd;d++) acc += rp[d] * w2[(size_t)d*4096 + j];
    W[tt] = acc > 0.f ? acc : 0.f;
  } else {
    int tt = (b-NB_TOK-NB_NODES-NB_RELID-NB_W)*256 + t;
    if(tt < Mm) deg[tt] = 0;
    else if(tt < Mm+8) S[tt-Mm] = 0.f;       // S[0..3] scalars, S[4] finisher counter
  }
}

// ---------------- K2: fused hist | U ----------------
__global__ __launch_bounds__(256) void k_mid(const int* __restrict__ ei,
    int* __restrict__ deg, const float* __restrict__ W,
    const float* __restrict__ a1w, const float* __restrict__ a2w,
    float* __restrict__ U1, float* __restrict__ U2){
  int b = blockIdx.x;
  const int t = threadIdx.x;
  if(b < NBM_HIST){
    int e = b*256 + t;
    if(e < Ee) atomicAdd(&deg[ei[Ee+e]], 1);
  } else {
    int tt = (b-NBM_HIST)*256 + t;           // R*64 = 3200
    if(tt < Rr*Dd){
      const float* wp = W + (size_t)(tt>>6)*4096 + (size_t)(tt&63)*Dd;
      float s1 = 0.f, s2 = 0.f;
      #pragma unroll 8
      for(int o=0;o<Dd;o++){ float w = wp[o]; s1 += w*a1w[Dd+o]; s2 += w*a2w[Dd+o]; }
      U1[tt] = s1; U2[tt] = s2;
    }
  }
}

// ---------------- CSR scan (block 0) + Y1 GEMM (blocks 1..NSCAN_Y) ----------------
// Y1[i][r] = sum_d x[i][d]*U1[r][d]; col 50 = p1[i]. 4 rows/wave: x values via
// wave-uniform float4 loads (no shfl); UT reads consecutive (conflict-free).
// Tail waves clamp the read base into x (duplicate rows write identical values).
__global__ __launch_bounds__(1024) void k_scan(const int* __restrict__ deg,
    int* __restrict__ rowptr, int* __restrict__ cursor,
    const float* __restrict__ x, const float* __restrict__ U1,
    const float* __restrict__ a1w, float* __restrict__ Y, float* __restrict__ p){
  __shared__ int ts[1024];
  __shared__ float UT[Dd][65];
  int t = threadIdx.x;
  if(blockIdx.x == 0){
    int base = t*24;
    int loc[24];
    int s = 0;
    #pragma unroll
    for(int j=0;j<24;j++){
      int idx = base+j;
      int d = (idx < Mm) ? deg[idx] : 0;
      loc[j] = s; s += d;
    }
    ts[t] = s;
    __syncthreads();
    for(int off=1; off<1024; off<<=1){
      int add = (t>=off) ? ts[t-off] : 0;
      __syncthreads();
      ts[t] += add;
      __syncthreads();
    }
    int excl = ts[t] - s;
    #pragma unroll
    for(int j=0;j<24;j++){
      int idx = base+j;
      if(idx < Mm){ int v = excl + loc[j]; rowptr[idx] = v; cursor[idx] = v; }
    }
    if(t==1023) rowptr[Mm] = ts[1023];
    return;
  }
  // ---- Y1 section ----
  for(int idx=t; idx<Rr*Dd; idx+=1024) UT[idx&63][idx>>6] = U1[idx];
  if(t < Dd){ UT[t][50] = a1w[t]; UT[t][51] = 0.f; }
  __syncthreads();
  const int lane = t&63;
  const int wv = __builtin_amdgcn_readfirstlane(t>>6);
  int i0 = (blockIdx.x-1)*64 + wv*4;
  if(i0 > Mm-4) i0 = Mm-4;                  // clamp: duplicate tail rows, in-bounds reads
  const int cl = lane < 51 ? lane : 51;
  const float* x0 = x + (size_t)i0*Dd;
  float acc0=0.f, acc1=0.f, acc2=0.f, acc3=0.f;
  #pragma unroll 4
  for(int k=0;k<Dd;k+=4){
    float4 q0 = *(const float4*)&x0[k];
    float4 q1 = *(const float4*)&x0[Dd+k];
    float4 q2 = *(const float4*)&x0[2*Dd+k];
    float4 q3 = *(const float4*)&x0[3*Dd+k];
    float u0=UT[k][cl], u1=UT[k+1][cl], u2=UT[k+2][cl], u3=UT[k+3][cl];
    acc0 += q0.x*u0 + q0.y*u1 + q0.z*u2 + q0.w*u3;
    acc1 += q1.x*u0 + q1.y*u1 + q1.z*u2 + q1.w*u3;
    acc2 += q2.x*u0 + q2.y*u1 + q2.z*u2 + q2.w*u3;
    acc3 += q3.x*u0 + q3.y*u1 + q3.z*u2 + q3.w*u3;
  }
  float av[4] = {acc0, acc1, acc2, acc3};
  #pragma unroll
  for(int r=0;r<4;r++){
    if(lane < 50) Y[(size_t)(i0+r)*50 + lane] = av[r];
    else if(lane == 50) p[i0+r] = av[r];
  }
}

// ---------------- Y2 GEMM: Y2[i][r] = relu(h[i]) . U2[r]; col 50 = p2 ----------------
// 4 rows/wave, wave-uniform h reads (no shfl loop).
__global__ __launch_bounds__(256) void k_y2(const float* __restrict__ h,
    const float* __restrict__ U2, const float* __restrict__ a2w,
    float* __restrict__ Y, float* __restrict__ p){
  __shared__ float UT[Dd][65];               // stride 65: conflict-free staging + reads
  const int t = threadIdx.x;
  for(int idx=t; idx<Rr*Dd; idx+=256) UT[idx&63][idx>>6] = U2[idx];
  if(t < Dd){ UT[t][50] = a2w[t]; UT[t][51] = 0.f; }
  __syncthreads();
  const int lane = t&63;
  const int wv = __builtin_amdgcn_readfirstlane(t>>6);
  const int i0 = blockIdx.x*16 + wv*4;
  const int cl = lane < 51 ? lane : 51;
  const float* h0 = h + (size_t)i0*Dd;
  float acc0=0.f, acc1=0.f, acc2=0.f, acc3=0.f;
  #pragma unroll 4
  for(int k=0;k<Dd;k+=4){
    float4 q0 = *(const float4*)&h0[k];
    float4 q1 = *(const float4*)&h0[Dd+k];
    float4 q2 = *(const float4*)&h0[2*Dd+k];
    float4 q3 = *(const float4*)&h0[3*Dd+k];
    q0.x=fmaxf(q0.x,0.f); q0.y=fmaxf(q0.y,0.f); q0.z=fmaxf(q0.z,0.f); q0.w=fmaxf(q0.w,0.f);
    q1.x=fmaxf(q1.x,0.f); q1.y=fmaxf(q1.y,0.f); q1.z=fmaxf(q1.z,0.f); q1.w=fmaxf(q1.w,0.f);
    q2.x=fmaxf(q2.x,0.f); q2.y=fmaxf(q2.y,0.f); q2.z=fmaxf(q2.z,0.f); q2.w=fmaxf(q2.w,0.f);
    q3.x=fmaxf(q3.x,0.f); q3.y=fmaxf(q3.y,0.f); q3.z=fmaxf(q3.z,0.f); q3.w=fmaxf(q3.w,0.f);
    float u0=UT[k][cl], u1=UT[k+1][cl], u2=UT[k+2][cl], u3=UT[k+3][cl];
    acc0 += q0.x*u0 + q0.y*u1 + q0.z*u2 + q0.w*u3;
    acc1 += q1.x*u0 + q1.y*u1 + q1.z*u2 + q1.w*u3;
    acc2 += q2.x*u0 + q2.y*u1 + q2.z*u2 + q2.w*u3;
    acc3 += q3.x*u0 + q3.y*u1 + q3.z*u2 + q3.w*u3;
  }
  float av[4] = {acc0, acc1, acc2, acc3};
  #pragma unroll
  for(int r=0;r<4;r++){
    if(lane < 50) Y[(size_t)(i0+r)*50 + lane] = av[r];
    else if(lane == 50) p[i0+r] = av[r];
  }
}

// ---------------- fused fill? | attention (1 thread per edge) ----------------
__global__ __launch_bounds__(256) void k_attf(const float* __restrict__ Y,
    const int* __restrict__ ei, const int* __restrict__ relid,
    const float* __restrict__ p, const float* __restrict__ ab,
    float* __restrict__ expa, float* __restrict__ S,
    int* __restrict__ cursor, int* __restrict__ eidx, int dofill){
  __shared__ float sr[4];
  int b = blockIdx.x;
  const int t = threadIdx.x, lane = t&63, wid = t>>6;
  if(dofill){
    if(b < NBA_FILL){
      int e = b*256 + t;
      if(e < Ee){
        int d = ei[Ee+e];
        int pos = atomicAdd(&cursor[d], 1);
        eidx[pos] = e;
      }
      return;
    }
    b -= NBA_FILL;
  }
  int e = b*256 + t;
  float ex = 0.f;
  if(e < Ee){
    int src = ei[e], dst = ei[Ee+e], r = relid[e];
    ex = expf(Y[(size_t)src*50 + r] + p[dst] + ab[0]);
    expa[e] = ex;
  }
  float acc = waveRed(ex);
  if(lane==0) sr[wid] = acc;
  __syncthreads();
  if(t==0) atomicAdd(S, sr[0]+sr[1]+sr[2]+sr[3]);
}

// ---------------- aggregate + fused root matmul ----------------
// Gather loop: lane-parallel index fetch + batched row loads (unchanged).
// Root matmul: wave-uniform x[dst] float4 reads x coalesced L1-hot root reads
// (replaces the 64-shfl broadcast loop that was LDS-pipe-bound ~30 us/launch).
__global__ __launch_bounds__(256) void k_aggr(const float* __restrict__ x,
    const int* __restrict__ ei, const int* __restrict__ rowptr,
    const int* __restrict__ eidx, const float* __restrict__ expa,
    const float* __restrict__ S, const float* __restrict__ root,
    const float* __restrict__ bias, float* __restrict__ y, int dorelu){
  int lane = threadIdx.x&63;
  int wid = __builtin_amdgcn_readfirstlane(threadIdx.x>>6);
  int dst = blockIdx.x*4 + wid;           // grid covers exactly Mm
  float invS = 1.f / S[0];
  int j0 = rowptr[dst], j1 = rowptr[dst+1];
  int deg = j1 - j0;
  float acc = 0.f;
  for(int base=0; base<deg; base+=64){
    int rem = deg - base;
    int n = rem < 64 ? rem : 64;
    float a = 0.f; int src = 0;
    if(lane < n){
      int e = eidx[j0 + base + lane];
      a = expa[e];
      src = ei[e];
    }
    for(int c=0; c<n; c+=8){               // c <= 56, so c+k <= 63: no shfl wrap
      float aj[8]; float xv[8];
      #pragma unroll
      for(int k=0;k<8;k++){
        int sj = __shfl(src, c+k, 64);
        aj[k]  = __shfl(a,   c+k, 64);
        xv[k]  = x[(size_t)sj*Dd + lane];
      }
      #pragma unroll
      for(int k=0;k<8;k++){
        float v = xv[k];
        if(dorelu) v = fmaxf(v, 0.f);
        acc += aj[k]*v;
      }
    }
  }
  acc *= invS;
  float rsum = bias[lane];
  const float* xr = x + (size_t)dst*Dd;
  #pragma unroll 4
  for(int k=0;k<Dd;k+=4){
    float4 xq = *(const float4*)&xr[k];
    if(dorelu){
      xq.x=fmaxf(xq.x,0.f); xq.y=fmaxf(xq.y,0.f);
      xq.z=fmaxf(xq.z,0.f); xq.w=fmaxf(xq.w,0.f);
    }
    rsum += xq.x*root[(size_t)k*Dd + lane];
    rsum += xq.y*root[(size_t)(k+1)*Dd + lane];
    rsum += xq.z*root[(size_t)(k+2)*Dd + lane];
    rsum += xq.w*root[(size_t)(k+3)*Dd + lane];
  }
  y[(size_t)dst*Dd + lane] = acc + rsum;
}

// ---------------- fused: out = fx @ w_lin2 + b_lin2 | kge loss | nt loss ----------------
// GEMM: 128x128 tiles, 8x8 per thread -> 64 FMA per 4 ds_read_b128 per k-iter:
// FMA-bound (ds fully hidden). LDS 65KB -> 2 blocks/CU. (round-5 structure, 58 us)
__global__ __launch_bounds__(256) void k_out(const float* __restrict__ fx,
    const float* __restrict__ w, const float* __restrict__ b,
    const int* __restrict__ ei, const int* __restrict__ relid,
    const float* __restrict__ rel, const int* __restrict__ lab,
    const float* __restrict__ wnt, const float* __restrict__ bnt,
    float* __restrict__ S, float* __restrict__ out){
  __shared__ float aT[Dd][132];
  __shared__ float ws[Dd][128];
  if(blockIdx.x < NGEMMT){
    const int bb = blockIdx.x;
    const int cg = bb / NGROW;                   // col chunk (0..5)
    const int bx = bb - cg*NGROW;                // row tile (0..188)
    const int t = threadIdx.x;
    const int r0 = bx*128, co = cg*128;
    // stage fx tile transposed: aT[k][r], 2048 float4s, 8/thread
    // (last tile reads past Mm land in workspace (W buffer) -- valid memory,
    //  values unused because stores are row-guarded)
    #pragma unroll
    for(int i=0;i<8;i++){
      int f = t + 256*i;
      int r = f>>4, k4 = (f&15)*4;
      float4 v = *(const float4*)&fx[(size_t)(r0+r)*Dd + k4];
      aT[k4+0][r]=v.x; aT[k4+1][r]=v.y; aT[k4+2][r]=v.z; aT[k4+3][r]=v.w;
    }
    // stage w chunk: ws[k][0..127] = w[k][co..co+127], 2048 float4s, 8/thread
    #pragma unroll
    for(int i=0;i<8;i++){
      int f = t + 256*i;
      int kk = f>>5, c4 = (f&31)*4;
      *(float4*)&ws[kk][c4] = *(const float4*)&w[(size_t)kk*TOK + co + c4];
    }
    __syncthreads();
    const int tr = t>>4, tc = t&15;
    const int rb = tr*8, cb = tc*4;              // rows rb..rb+7, cols cb..+3 & cb+64..+67
    float4 bv0 = *(const float4*)&b[co+cb];
    float4 bv1 = *(const float4*)&b[co+64+cb];
    float acc[8][8];
    #pragma unroll
    for(int i=0;i<8;i++){
      acc[i][0]=bv0.x; acc[i][1]=bv0.y; acc[i][2]=bv0.z; acc[i][3]=bv0.w;
      acc[i][4]=bv1.x; acc[i][5]=bv1.y; acc[i][6]=bv1.z; acc[i][7]=bv1.w;
    }
    #pragma unroll 4
    for(int k=0;k<Dd;k++){
      float4 a0 = *(const float4*)&aT[k][rb];
      float4 a1 = *(const float4*)&aT[k][rb+4];
      float4 w0 = *(const float4*)&ws[k][cb];
      float4 w1 = *(const float4*)&ws[k][cb+64];
      float av[8] = {a0.x,a0.y,a0.z,a0.w,a1.x,a1.y,a1.z,a1.w};
      float wv[8] = {w0.x,w0.y,w0.z,w0.w,w1.x,w1.y,w1.z,w1.w};
      #pragma unroll
      for(int i=0;i<8;i++){
        #pragma unroll
        for(int j=0;j<8;j++) acc[i][j] += av[i]*wv[j];
      }
    }
    #pragma unroll
    for(int i=0;i<8;i++){
      int row = r0 + rb + i;
      if(row < Mm){
        float4 o0; o0.x=acc[i][0]; o0.y=acc[i][1]; o0.z=acc[i][2]; o0.w=acc[i][3];
        float4 o1; o1.x=acc[i][4]; o1.y=acc[i][5]; o1.z=acc[i][6]; o1.w=acc[i][7];
        *(float4*)&out[(size_t)row*TOK + co + cb] = o0;
        *(float4*)&out[(size_t)row*TOK + co + 64 + cb] = o1;
      }
    }
    return;
  }
  // ---- loss blocks ----
  {
    __shared__ float sr[4];
    const int lb2 = blockIdx.x - NGEMMT;         // 0..NFIN-1
    const int t = threadIdx.x, lane = t&63, wid = t>>6;
    float acc = 0.f;
    int slot;
    if(lb2 < NKGE){
      // kge loss: per wave, coalesce-load 64 edges' indices, then branchless
      // masked gathers (all loads independent -> deep pipelining under unroll).
      slot = 2;
      const int cb = (lb2*4 + wid)*64;           // chunk base edge
      int e = cb + lane;
      bool vld = e < Ee;
      int sv = vld ? ei[e]    : 0;
      int dv = vld ? ei[Ee+e] : 0;
      int rv = vld ? relid[e] : 47;              // r>=47 -> masked out
      #pragma unroll 8
      for(int j=0;j<64;j++){
        int r = __shfl(rv, j, 64);
        int s = __shfl(sv, j, 64);
        int d = __shfl(dv, j, 64);
        float m = (r < 47) ? 1.f : 0.f;
        float diff = fx[(size_t)s*Dd + lane] + rel[r*Dd + lane] - fx[(size_t)d*Dd + lane];
        acc += m*diff*diff;
      }
      acc = waveRed(acc);
    } else {
      // nt loss: one row per thread, streaming read of fx
      slot = 3;
      int i = (lb2 - NKGE)*256 + t;
      float contrib = 0.f;
      if(i < Mm){
        const float* r = fx + (size_t)i*Dd;
        float l0 = bnt[0], l1 = bnt[1], l2 = bnt[2];
        #pragma unroll 8
        for(int k=0;k<Dd;k++){
          float f = r[k];
          l0 += f*wnt[k*3+0]; l1 += f*wnt[k*3+1]; l2 += f*wnt[k*3+2];
        }
        float mx = fmaxf(l0, fmaxf(l1,l2));
        float lse = logf(expf(l0-mx)+expf(l1-mx)+expf(l2-mx)) + mx;
        int lb = lab[i];
        float lp = (lb==0 ? l0 : (lb==1 ? l1 : l2)) - lse;
        contrib = -lp;
      }
      acc = waveRed(contrib);
    }
    if(lane==0) sr[wid] = acc;
    __syncthreads();
    if(t==0){
      atomicAdd(&S[slot], sr[0]+sr[1]+sr[2]+sr[3]);
      __threadfence();
      int prev = atomicAdd((int*)&S[4], 1);      // finisher counter (zeroed in k_prep)
      if(prev == NFIN-1){
        float v2 = atomicAdd(&S[2], 0.f);        // device-scope coherent read
        float v3 = atomicAdd(&S[3], 0.f);
        size_t base = (size_t)Mm*TOK;
        out[base+0] = v2 / (float)(Ee*Dd);
        out[base+1] = v3 / (float)Mm;
      }
    }
  }
}

extern "C" void kernel_launch(void* const* d_in, const int* in_sizes, int n_in,
                              void* d_out, int out_size, void* d_ws, size_t ws_size,
                              hipStream_t stream) {
  const int*   node_ids = (const int*)d_in[0];
  const int*   ei       = (const int*)d_in[1];
  const float* eattr    = (const float*)d_in[2];
  const float* tokemb   = (const float*)d_in[3];
  const int*   labels   = (const int*)d_in[4];
  const float* kg       = (const float*)d_in[5];
  const float* rel      = (const float*)d_in[6];
  const float* w_e2     = (const float*)d_in[7];
  const float* b_e2     = (const float*)d_in[8];
  const float* a1w      = (const float*)d_in[9];
  const float* a1b      = (const float*)d_in[10];
  const float* root1    = (const float*)d_in[11];
  const float* bias1    = (const float*)d_in[12];
  const float* a2w      = (const float*)d_in[13];
  const float* a2b      = (const float*)d_in[14];
  const float* root2    = (const float*)d_in[15];
  const float* bias2    = (const float*)d_in[16];
  const float* wlin1    = (const float*)d_in[17];
  const float* blin1    = (const float*)d_in[18];
  const float* wlin2    = (const float*)d_in[19];
  const float* blin2    = (const float*)d_in[20];
  const float* wnt      = (const float*)d_in[21];
  const float* bnt      = (const float*)d_in[22];

  float* wsb = (float*)d_ws;
  float* x    = wsb;                      // M*64
  float* h    = x  + (size_t)Mm*Dd;
  float* fx   = h  + (size_t)Mm*Dd;       // also hosts Y (M*50) before aggr2 writes it
  float* W    = fx + (size_t)Mm*Dd;       // 50*4096
  float* U1   = W  + Rr*4096;             // 3200
  float* U2   = U1 + Rr*Dd;
  float* expa = U2 + Rr*Dd;               // E
  float* p    = expa + Ee;                // M
  float* S    = p + Mm;                   // 8: den1, den2, kge, nt, counter, pad
  int* relid  = (int*)(S + 8);            // E
  int* deg    = relid + Ee;               // M
  int* rowptr = deg + Mm;                 // M+1
  int* cursor = rowptr + Mm + 1;          // M
  int* eidx   = cursor + Mm;              // E
  float* Y    = fx;                       // alias: Y1/Y2 live in fx until aggr2
  float* out  = (float*)d_out;

  // ---- prep + CSR + Y1 ----
  k_prep<<<NB_TOK+NB_NODES+NB_RELID+NB_W+NB_ZERO, 256, 0, stream>>>(
      tokemb, wlin1, blin1, node_ids, kg, eattr, relid, rel, w_e2, b_e2, W, deg, S, x);
  k_mid <<<NBM_HIST+NBM_U, 256, 0, stream>>>(ei, deg, W, a1w, a2w, U1, U2);
  k_scan<<<1+NSCAN_Y, 1024, 0, stream>>>(deg, rowptr, cursor, x, U1, a1w, Y, p);

  // ---- layer 1: x -> h (attf also bucket-fills eidx) ----
  k_attf<<<NBA_FILL+NBA_ATT, 256, 0, stream>>>(Y, ei, relid, p, a1b, expa, S,
                                               cursor, eidx, 1);
  k_aggr<<<Mm/4, 256, 0, stream>>>(x, ei, rowptr, eidx, expa, S, root1, bias1, h, 0);

  // ---- layer 2: relu(h) -> fx (Y2/p2 precomputed from h) ----
  k_y2  <<<Mm/16, 256, 0, stream>>>(h, U2, a2w, Y, p);
  k_attf<<<NBA_ATT, 256, 0, stream>>>(Y, ei, relid, p, a2b, expa, S+1,
                                      (int*)0, (int*)0, 0);
  k_aggr<<<Mm/4, 256, 0, stream>>>(h, ei, rowptr, eidx, expa, S+1, root2, bias2, fx, 1);

  // ---- fused output GEMM + kge-loss + nt-loss (+ scalar finisher) ----
  k_out <<<NGEMMT + NFIN, 256, 0, stream>>>(
      fx, wlin2, blin2, ei, relid, rel, labels, wnt, bnt, S, out);
}